// Round 4
// baseline (449.324 us; speedup 1.0000x reference)
//
#include <hip/hip_runtime.h>

#define NT 512
#define ROWLEN 16384
#define PT 8      // u32x4 per thread: 8 * 4 * 512 = 16384 floats
#define CAP 4096  // candidate buffer entries (16 KB)

typedef unsigned int u32x4 __attribute__((ext_vector_type(4)));

__device__ inline unsigned mbcnt64(unsigned long long m) {
  unsigned lo = __builtin_amdgcn_mbcnt_lo((unsigned)m, 0u);
  return __builtin_amdgcn_mbcnt_hi((unsigned)(m >> 32), lo);
}

// Descending (suffix) bin selection over NB bins with NT threads.
// Finds bin b with count(bins > b) < krem <= count(bins >= b).
// sel[0] = b, sel[1] = krem - count(bins > b).
template<int NB>
__device__ inline void select_bin(unsigned* hist, unsigned* wtot,
                                  unsigned* sel, unsigned tid, unsigned krem) {
  constexpr int BPT = NB / NT;
  constexpr int NW = NT / 64;
  const unsigned base = tid * BPT;
  unsigned c[BPT];
  unsigned s = 0;
#pragma unroll
  for (int i = 0; i < BPT; i++) { c[i] = hist[base + i]; s += c[i]; }

  const unsigned lane = tid & 63u;
  const unsigned wid  = tid >> 6;

  // inclusive suffix sum within the wave (sum over lanes >= lane)
  unsigned suf = s;
#pragma unroll
  for (int off = 1; off < 64; off <<= 1) {
    unsigned v = __shfl_down(suf, off);
    if (lane + off < 64) suf += v;
  }
  if (lane == 0) wtot[wid] = suf;
  __syncthreads();

  unsigned above = suf - s;  // elements in higher bins within this wave
  for (unsigned w = wid + 1; w < NW; w++) above += wtot[w];

#pragma unroll
  for (int i = BPT - 1; i >= 0; i--) {
    unsigned cc = c[i];
    if (above < krem && above + cc >= krem) {
      sel[0] = base + (unsigned)i;
      sel[1] = krem - above;
    }
    above += cc;
  }
  __syncthreads();
}

__global__ __launch_bounds__(NT, 5)
void topk_act_kernel(const float* __restrict__ x, float* __restrict__ out,
                     const int* __restrict__ kp) {
  __shared__ unsigned hist1[2048];
  __shared__ unsigned hist2[1024];
  __shared__ unsigned hist3[1024];
  __shared__ unsigned cand[CAP];
  __shared__ unsigned wtot[NT / 64];
  __shared__ unsigned sel[2];
  __shared__ unsigned cnt;

  const unsigned tid = threadIdx.x;
  const unsigned k = (unsigned)*kp;
  const size_t rowoff = (size_t)blockIdx.x * (size_t)ROWLEN;
  const u32x4* __restrict__ xr = reinterpret_cast<const u32x4*>(x + rowoff);
  u32x4* __restrict__ orow     = reinterpret_cast<u32x4*>(out + rowoff);

  // coalesced nontemporal load: 32 floats/thread in registers
  u32x4 d[PT];
#pragma unroll
  for (int j = 0; j < PT; j++) d[j] = __builtin_nontemporal_load(&xr[tid + j * NT]);

  // zero everything up front (overlaps with loads in flight)
#pragma unroll
  for (int i = 0; i < 2048 / NT; i++) hist1[tid + i * NT] = 0u;
#pragma unroll
  for (int i = 0; i < 1024 / NT; i++) hist2[tid + i * NT] = 0u;
#pragma unroll
  for (int i = 0; i < 1024 / NT; i++) hist3[tid + i * NT] = 0u;
  if (tid == 0) cnt = 0u;
  __syncthreads();

  // ---- level 1: 2048 bins over a>>21, where a = u<<1 (sign dropped) ----
#pragma unroll
  for (int j = 0; j < PT; j++) {
    atomicAdd(&hist1[(d[j].x << 1) >> 21], 1u);
    atomicAdd(&hist1[(d[j].y << 1) >> 21], 1u);
    atomicAdd(&hist1[(d[j].z << 1) >> 21], 1u);
    atomicAdd(&hist1[(d[j].w << 1) >> 21], 1u);
  }
  __syncthreads();
  select_bin<2048>(hist1, wtot, sel, tid, k);
  const unsigned P1 = sel[0];
  const unsigned r1 = sel[1];

  // ---- gather candidates (wave-aggregated atomics) ----
  {
    auto push = [&](unsigned a) {
      bool p = (a >> 21) == P1;
      unsigned long long m = __ballot(p);
      if (m) {  // wave-uniform
        unsigned nw = (unsigned)__popcll(m);
        if (p) {
          unsigned pre = mbcnt64(m);  // matching lanes below me
          unsigned b = 0;
          if (pre == 0) b = atomicAdd(&cnt, nw);     // first matching lane only
          b = __builtin_amdgcn_readfirstlane(b);     // broadcast its base
          unsigned i = b + pre;
          if (i < CAP) cand[i] = a;
        }
      }
    };
#pragma unroll
    for (int j = 0; j < PT; j++) {
      push(d[j].x << 1); push(d[j].y << 1); push(d[j].z << 1); push(d[j].w << 1);
    }
  }
  __syncthreads();
  const unsigned n = cnt;

  // ---- level 2: bins over bits (a>>11)&0x3FF ----
  if (n <= CAP) {
    for (unsigned i = tid; i < n; i += NT)
      atomicAdd(&hist2[(cand[i] >> 11) & 0x3FFu], 1u);
  } else {  // overflow fallback: full register scan
#pragma unroll
    for (int j = 0; j < PT; j++) {
      unsigned a;
      a = d[j].x << 1; if ((a >> 21) == P1) atomicAdd(&hist2[(a >> 11) & 0x3FFu], 1u);
      a = d[j].y << 1; if ((a >> 21) == P1) atomicAdd(&hist2[(a >> 11) & 0x3FFu], 1u);
      a = d[j].z << 1; if ((a >> 21) == P1) atomicAdd(&hist2[(a >> 11) & 0x3FFu], 1u);
      a = d[j].w << 1; if ((a >> 21) == P1) atomicAdd(&hist2[(a >> 11) & 0x3FFu], 1u);
    }
  }
  __syncthreads();
  select_bin<1024>(hist2, wtot, sel, tid, r1);
  const unsigned P2 = sel[0];
  const unsigned r2 = sel[1];

  // ---- level 3: bins over bits (a>>1)&0x3FF ----
  if (n <= CAP) {
    for (unsigned i = tid; i < n; i += NT) {
      unsigned a = cand[i];
      if (((a >> 11) & 0x3FFu) == P2) atomicAdd(&hist3[(a >> 1) & 0x3FFu], 1u);
    }
  } else {
    const unsigned P12 = (P1 << 10) | P2;
#pragma unroll
    for (int j = 0; j < PT; j++) {
      unsigned a;
      a = d[j].x << 1; if ((a >> 11) == P12) atomicAdd(&hist3[(a >> 1) & 0x3FFu], 1u);
      a = d[j].y << 1; if ((a >> 11) == P12) atomicAdd(&hist3[(a >> 1) & 0x3FFu], 1u);
      a = d[j].z << 1; if ((a >> 11) == P12) atomicAdd(&hist3[(a >> 1) & 0x3FFu], 1u);
      a = d[j].w << 1; if ((a >> 11) == P12) atomicAdd(&hist3[(a >> 1) & 0x3FFu], 1u);
    }
  }
  __syncthreads();
  select_bin<1024>(hist3, wtot, sel, tid, r2);
  const unsigned Va = (P1 << 21) | (P2 << 11) | (sel[0] << 1);  // k-th largest, a-space

  // ---- final: mask and nontemporal write ----
#pragma unroll
  for (int j = 0; j < PT; j++) {
    u32x4 o;
    o.x = ((d[j].x << 1) >= Va) ? d[j].x : 0u;
    o.y = ((d[j].y << 1) >= Va) ? d[j].y : 0u;
    o.z = ((d[j].z << 1) >= Va) ? d[j].z : 0u;
    o.w = ((d[j].w << 1) >= Va) ? d[j].w : 0u;
    __builtin_nontemporal_store(o, &orow[tid + j * NT]);
  }
}

extern "C" void kernel_launch(void* const* d_in, const int* in_sizes, int n_in,
                              void* d_out, int out_size, void* d_ws, size_t ws_size,
                              hipStream_t stream) {
  const float* x   = (const float*)d_in[0];
  const int*   kp  = (const int*)d_in[1];
  float*       out = (float*)d_out;
  const int rows = out_size / ROWLEN;  // 4096
  topk_act_kernel<<<rows, NT, 0, stream>>>(x, out, kp);
}